// Round 10
// baseline (433.712 us; speedup 1.0000x reference)
//
#include <hip/hip_runtime.h>
#include <math.h>

// Problem constants (B=1)
#define MM 1024
#define DD 512
#define CC 128
#define LDSR 516   // A row stride in ushorts: 1032 B = 258 dw ≡ 2 (mod 32).
                   // b64 reads/8B stores: uniform 4 accesses/bank/wave = 2/phase -> free.

// ws layout (floats):
//  H[1024][3072]      @ 0        (cols 1024.. src_proj, 2048.. ant_proj; 0..1023 unused)
//  slow[1024][128]    @ 3145728
//  spk_proj[2][1024]  @ 3276800
//  bkt_proj[10][1024] @ 3278848
//  ms[1024]           @ 3289088   (raw dot partials, atomically accumulated; no b1)
//  lossp[1024]        @ 3290112
//  embb bf16[1024][512]  @ 3291136
//  Wall bf16[4096][512]  @ 3553280
//    rows [0,1024)=ms_W0^T, [1024,2048)=W_src^T, [2048,3072)=W_ant^T
//    region [3072,4096) reused as WfragB (32x32 fragment-major W_prod, = r0-r6 Wfrag):
//      [tile t:32][kstep s:32][lane:64][8] bf16
//      element (f = t*32 + (lane&31), k = s*16 + (lane>>5)*8 + j) at ((t*32+s)*64+lane)*8+j

typedef __attribute__((ext_vector_type(8))) short bf16x8;
typedef __attribute__((ext_vector_type(4), aligned(8))) short bf16x4a;
typedef __attribute__((ext_vector_type(4))) float f32x4;
typedef __attribute__((ext_vector_type(16))) float f32x16;

__device__ __forceinline__ ushort bf16_rn(float x) {
    uint u = __float_as_uint(x);
    uint r = u + 0x7fffu + ((u >> 16) & 1u);
    return (ushort)(r >> 16);
}
__device__ __forceinline__ float bf16_to_f(ushort u) {
    return __uint_as_float(((uint)u) << 16);
}
__device__ __forceinline__ bf16x8 ld_lds16(const ushort* p) {   // two ds_read_b64 (8B-aligned)
    bf16x4a lo = *(const bf16x4a*)p;
    bf16x4a hi = *(const bf16x4a*)(p + 4);
    return __builtin_shufflevector(lo, hi, 0, 1, 2, 3, 4, 5, 6, 7);
}

// ---------------- prep_all: emb->bf16 | Wall transpose | WfragB | small projections + ms zero
// grid ranges: [0,1024) emb; [1024,1408) wall; [1408,1664) wfragB; [1664,1676) small_proj
__global__ __launch_bounds__(256) void prep_all(
    const float* __restrict__ emb, ushort* __restrict__ embb,
    const float* __restrict__ ms_W0, const float* __restrict__ sp_W0,
    ushort* __restrict__ Wall, ushort* __restrict__ WfragB,
    const float* __restrict__ speaker_emb, const float* __restrict__ bucket_emb,
    float* __restrict__ spk_proj, float* __restrict__ bkt_proj,
    float* __restrict__ msc)
{
    const int bid = blockIdx.x;
    const int tid = threadIdx.x;

    if (bid < 1024) {                               // ---- prep_emb
        int i = bid * 256 + tid;
        float2 v = ((const float2*)emb)[i];
        ushort2 o;
        o.x = bf16_rn(v.x);
        o.y = bf16_rn(v.y);
        ((ushort2*)embb)[i] = o;
        return;
    }
    if (bid < 1408) {                               // ---- prep_wall
        __shared__ float t[64][65];
        const int r = bid - 1024;                   // 0..383
        const int k0 = (r & 7) * 64;
        const int n0 = (r >> 3) * 64;
        const int g = n0 >> 10;
        const float* src = (g == 0) ? ms_W0 : (sp_W0 + (size_t)(g - 1) * 512 * 1024);
        const int col0 = n0 & 1023;
        const int tr = tid >> 6, tc = tid & 63;
#pragma unroll
        for (int i = 0; i < 16; ++i) {
            int k = tr + i * 4;
            t[k][tc] = src[(size_t)(k0 + k) * 1024 + col0 + tc];
        }
        __syncthreads();
        const int f = tid >> 2;
        const int c4 = tid & 3;
        ushort tmp[16];
#pragma unroll
        for (int j = 0; j < 16; ++j) tmp[j] = bf16_rn(t[c4 * 16 + j][f]);
        uint4* dst = (uint4*)(Wall + (size_t)(n0 + f) * 512 + k0 + c4 * 16);
        dst[0] = *(uint4*)&tmp[0];
        dst[1] = *(uint4*)&tmp[8];
        return;
    }
    if (bid < 1664) {                               // ---- prep_wfragB (4 ts per block)
        const int ts = (bid - 1408) * 4 + (tid >> 6);   // 0..1023 = t*32 + s
        const int l = tid & 63;
        const int tt = ts >> 5, s = ts & 31;
        const int f = tt * 32 + (l & 31);
        const int kb = s * 16 + (l >> 5) * 8;
        const float* W = sp_W0 + (size_t)1024 * 1024;   // W_prod [k=512][f=1024]
        ushort tmp[8];
#pragma unroll
        for (int e = 0; e < 8; ++e) tmp[e] = bf16_rn(W[(size_t)(kb + e) * 1024 + f]);
        uint4* dst = (uint4*)(WfragB + (size_t)ts * 512 + l * 8);
        *dst = *(uint4*)&tmp[0];
        return;
    }
    {                                               // ---- small_proj (+ msc zero in r==0)
        const int r = bid - 1664;                   // 0..11
        if (r == 0) {
            for (int i = tid; i < 1024; i += 256) msc[i] = 0.f;
        }
        const float* e; const float* W; float* out;
        if (r < 2) { e = speaker_emb + r * 20; W = sp_W0 + (size_t)1536 * 1024; out = spk_proj + r * 1024; }
        else       { e = bucket_emb + (r - 2) * 20; W = sp_W0 + (size_t)1556 * 1024; out = bkt_proj + (r - 2) * 1024; }
        float ek[20];
#pragma unroll
        for (int k = 0; k < 20; ++k) ek[k] = e[k];
        for (int f = tid; f < 1024; f += 256) {
            float s = 0.f;
#pragma unroll
            for (int k = 0; k < 20; ++k) s = fmaf(ek[k], W[(size_t)k * 1024 + f], s);
            out[f] = s;
        }
        return;
    }
}

// ---------------- H = emb @ [ms_W0 | W_src | W_ant] via MFMA, 64x64 tiles (768 blocks
// -> 3 blocks/CU; the old 192-block grid was latency-bound at 0.75 blocks/CU).
// ms-hidden region (n<1024) consumed in-register -> atomicAdd(ms), not stored.
__global__ __launch_bounds__(256) void gemm_h_ms(
    const ushort* __restrict__ embb, const ushort* __restrict__ Wall,
    const float* __restrict__ ms_b0, const float* __restrict__ ms_W1,
    float* __restrict__ H, float* __restrict__ ms)
{
    const int n0 = blockIdx.x * 64;   // 48
    const int m0 = blockIdx.y * 64;   // 16
    const int lane = threadIdx.x & 63, wave = threadIdx.x >> 6;
    const int wx = wave & 1, wy = wave >> 1;
    const int l15 = lane & 15, lq = lane >> 4;

    const ushort* arow[2];
#pragma unroll
    for (int mi = 0; mi < 2; ++mi)
        arow[mi] = embb + (size_t)(m0 + wy * 32 + mi * 16 + l15) * 512;
    const ushort* brow[2];
#pragma unroll
    for (int ni = 0; ni < 2; ++ni)
        brow[ni] = Wall + (size_t)(n0 + wx * 32 + ni * 16 + l15) * 512;

    f32x4 acc[2][2];
#pragma unroll
    for (int i = 0; i < 2; ++i)
#pragma unroll
        for (int j = 0; j < 2; ++j) acc[i][j] = (f32x4)0.f;

    for (int kt = 0; kt < 512; kt += 32) {
        const int ko = kt + lq * 8;
        bf16x8 av[2], bv[2];
#pragma unroll
        for (int mi = 0; mi < 2; ++mi) av[mi] = *(const bf16x8*)(arow[mi] + ko);
#pragma unroll
        for (int ni = 0; ni < 2; ++ni) bv[ni] = *(const bf16x8*)(brow[ni] + ko);
#pragma unroll
        for (int mi = 0; mi < 2; ++mi)
#pragma unroll
            for (int ni = 0; ni < 2; ++ni)
                acc[mi][ni] = __builtin_amdgcn_mfma_f32_16x16x32_bf16(av[mi], bv[ni], acc[mi][ni], 0, 0, 0);
    }

    if (n0 < 1024) {
        float b0v[2], w1v[2];
#pragma unroll
        for (int ni = 0; ni < 2; ++ni) {
            const int col = n0 + wx * 32 + ni * 16 + l15;
            b0v[ni] = ms_b0[col];
            w1v[ni] = ms_W1[col];
        }
#pragma unroll
        for (int mi = 0; mi < 2; ++mi)
#pragma unroll
            for (int r = 0; r < 4; ++r) {
                float s = 0.f;
#pragma unroll
                for (int ni = 0; ni < 2; ++ni)
                    s += fmaxf(acc[mi][ni][r] + b0v[ni], 0.f) * w1v[ni];
                s += __shfl_xor(s, 1); s += __shfl_xor(s, 2);
                s += __shfl_xor(s, 4); s += __shfl_xor(s, 8);
                if (l15 == 0) {
                    const int mrow = m0 + wy * 32 + mi * 16 + lq * 4 + r;
                    atomicAdd(&ms[mrow], s);
                }
            }
    } else {
#pragma unroll
        for (int mi = 0; mi < 2; ++mi)
#pragma unroll
            for (int r = 0; r < 4; ++r) {
                int mrow = m0 + wy * 32 + mi * 16 + lq * 4 + r;
#pragma unroll
                for (int ni = 0; ni < 2; ++ni)
                    H[(size_t)mrow * 3072 + n0 + wx * 32 + ni * 16 + l15] = acc[mi][ni][r];
            }
    }
}

// ---------------- pair scorer v10: 32x32x16 MFMA (1 instr/k-step; issue count halved,
// matrix cycles -17% vs 4x 16x16x32), same 8-waves/SIMD occupancy skeleton as r8/r9.
// Grid (1024 m, 4 cq); 512 thr / 8 waves; A-tile 32c x 512k in LDS -> 4 blocks/CU.
// Wave covers 32c x 128f via ft=0..3; acc = one f32x16 (16 AGPR); sacc[16] deferred
// reduce. Epilogue metadata (a*3072, bk<<10, ss) precomputed in LDS: no per-reg
// clamp/mul chains. A/B/C-D layouts identical to the r0-r6 verified 32x32 path.
__global__ __launch_bounds__(512, 8) void pair_mfma(
    const ushort* __restrict__ embb, const ushort* __restrict__ WfragB,
    const float* __restrict__ H, const float* __restrict__ spk_proj,
    const float* __restrict__ bkt_proj, const float* __restrict__ sp_b0,
    const float* __restrict__ sp_W1, const int* __restrict__ speaker,
    float* __restrict__ slow)
{
    extern __shared__ ushort Alds[];                  // 32*LDSR ushorts
    float* red = (float*)(Alds + 32 * LDSR);          // 8*32 floats
    int* meta_ai = (int*)(red + 8 * 32);              // 32 ints: a*3072
    int* meta_sb = meta_ai + 32;                      // 32 ints: same-speaker flag
    int* meta_bi = meta_sb + 32;                      // 32 ints: bucket<<10
    const int m = blockIdx.x;
    const int cq = blockIdx.y;                        // c-quarter
    const int cbase = cq * 32;
    const int tid = threadIdx.x;
    const int spk_m = speaker[m];

    // ---- build A[c][k] = bf16(em[k]*ea[k]) in LDS + per-c metadata (32 rows)
    {
        const int c = tid & 31;
        const int kh = (tid >> 5) * 32;               // 16 chunks of 32 ushorts
        int a = m - 1 - (cbase + c); if (a < 0) a = 0;
        const ushort* ea = embb + (size_t)a * 512 + kh;
        const ushort* em = embb + (size_t)m * 512 + kh;
        ushort* dst = Alds + c * LDSR + kh;
#pragma unroll
        for (int j = 0; j < 32; j += 8) {
            bf16x8 va = *(const bf16x8*)(ea + j);
            bf16x8 vm = *(const bf16x8*)(em + j);
            uint pr[4];
#pragma unroll
            for (int p = 0; p < 4; ++p) {
                float q0 = bf16_to_f((ushort)va[2 * p])     * bf16_to_f((ushort)vm[2 * p]);
                float q1 = bf16_to_f((ushort)va[2 * p + 1]) * bf16_to_f((ushort)vm[2 * p + 1]);
                pr[p] = __builtin_amdgcn_perm(__float_as_uint(q1), __float_as_uint(q0), 0x07060302u);
            }
            *(uint2*)(dst + j)     = *(uint2*)&pr[0];   // 8B stores (rows are 8B-aligned)
            *(uint2*)(dst + j + 4) = *(uint2*)&pr[2];
        }
        if (tid < 32) {                               // c == tid, a as computed above
            meta_sb[c] = (speaker[a] == spk_m) ? 1 : 0;
            meta_ai[c] = a * 3072;
            int off = cbase + c + 1;                  // 1..128
            int bk;
            if (off <= 4) bk = off;
            else { bk = 31 - __clz(off) + 3; if (bk > 9) bk = 9; }
            meta_bi[c] = bk << 10;
        }
    }
    __syncthreads();

    const int lane = tid & 63;
    const int wave = __builtin_amdgcn_readfirstlane(tid >> 6);   // 0..7, wave-uniform
    const int l31 = lane & 31, k5 = lane >> 5;
    const ushort* ab0 = Alds + l31 * LDSR + k5 * 8;   // A frag: row=l31, k-chunk=k5*8

    const float* Hsrc = H + m * 3072 + 1024;          // block-uniform
    const float* Hant = H + 2048;

    float sacc[16];
#pragma unroll
    for (int r = 0; r < 16; ++r) sacc[r] = 0.f;

#pragma unroll 1
    for (int ft = 0; ft < 4; ++ft) {
        // B: tile t = wave*4+ft; per s-step 1 KB contiguous, 1024B stride (imm-foldable)
        const ushort* bb = WfragB + (size_t)(wave * 4 + ft) * 16384 + (size_t)lane * 8;
        f32x16 acc = (f32x16)0.f;

#pragma unroll 4
        for (int s = 0; s < 32; ++s) {
            bf16x8 b = *(const bf16x8*)(bb + s * 512);
            bf16x8 a = ld_lds16(ab0 + s * 16);
            __builtin_amdgcn_s_setprio(1);
            acc = __builtin_amdgcn_mfma_f32_32x32x16_bf16(a, b, acc, 0, 0, 0);
            __builtin_amdgcn_s_setprio(0);
        }

        // ---- per-ft epilogue: fold into sacc
        const int fcol = wave * 128 + ft * 32 + l31;
        const float srcb = Hsrc[fcol] + sp_b0[fcol];
        const float w1v  = sp_W1[fcol];
        const float sp0  = spk_proj[fcol] + srcb;
        const float sp1  = spk_proj[1024 + fcol] + srcb;
        // C/D 32x32: col(f)=l31, row(c) = (reg&3)+8*(reg>>2)+4*k5
#pragma unroll
        for (int reg = 0; reg < 16; ++reg) {
            const int cl = (reg & 3) + 8 * (reg >> 2) + 4 * k5;
            const float spsel = meta_sb[cl] ? sp1 : sp0;
            float pre = acc[reg] + spsel + Hant[meta_ai[cl] + fcol]
                      + bkt_proj[meta_bi[cl] + fcol];
            sacc[reg] += fmaxf(pre, 0.f) * w1v;
        }
    }

    // ---- single deferred reduce per reg (f-sum over l31, within each 32-lane half)
#pragma unroll
    for (int reg = 0; reg < 16; ++reg) {
        float s = sacc[reg];
        s += __shfl_xor(s, 1); s += __shfl_xor(s, 2);
        s += __shfl_xor(s, 4); s += __shfl_xor(s, 8); s += __shfl_xor(s, 16);
        if (l31 == 0) red[wave * 32 + (reg & 3) + 8 * (reg >> 2) + 4 * k5] = s;
    }
    __syncthreads();
    if (tid < 32) {
        float s = 0.f;
#pragma unroll
        for (int i = 0; i < 8; ++i) s += red[i * 32 + tid];
        slow[m * 128 + cbase + tid] = s;
    }
}

// ---------------- softmax + per-mention loss (ms = raw dots; b1 added here, 2x)
__device__ __forceinline__ float bsum2(float v, float* sm) {
#pragma unroll
    for (int o = 1; o < 64; o <<= 1) v += __shfl_xor(v, o);
    __syncthreads();
    if ((threadIdx.x & 63) == 0) sm[threadIdx.x >> 6] = v;
    __syncthreads();
    return sm[0] + sm[1];
}
__device__ __forceinline__ float bmax2(float v, float* sm) {
#pragma unroll
    for (int o = 1; o < 64; o <<= 1) v = fmaxf(v, __shfl_xor(v, o));
    __syncthreads();
    if ((threadIdx.x & 63) == 0) sm[threadIdx.x >> 6] = v;
    __syncthreads();
    return fmaxf(sm[0], sm[1]);
}

__global__ __launch_bounds__(128) void softmax_loss(
    const float* __restrict__ slow, const float* __restrict__ ms,
    const float* __restrict__ ms_b1,
    const float* __restrict__ sp_b1, const int* __restrict__ cluster,
    float* __restrict__ out, float* __restrict__ loss_partial)
{
    const int m = blockIdx.x, c = threadIdx.x;
    __shared__ float sm[2];
    const int raw = m - 1 - c;
    const bool maskv = raw >= 0;
    const int a = maskv ? raw : 0;
    float score = slow[(size_t)m * 128 + c] + sp_b1[0]
                + ms[m] + ms[a] + 2.f * ms_b1[0];
    if (!maskv) score = -INFINITY;

    float mx = fmaxf(bmax2(score, sm), 0.f);
    float e = expf(score - mx);
    float e0 = expf(0.f - mx);
    float sum = bsum2(e, sm) + e0;
    float p = e / sum, p0 = e0 / sum;
    const float eps = 1e-6f;
    p  = fminf(fmaxf(p,  eps), 1.f - eps);
    p0 = fminf(fmaxf(p0, eps), 1.f - eps);
    float sum2 = bsum2(p, sm) + p0;
    p /= sum2; p0 /= sum2;
    out[(size_t)m * 129 + 1 + c] = p;
    if (c == 0) out[(size_t)m * 129] = p0;

    const int cid = cluster[m];
    const bool lbl = maskv && (cid > 0) && (cluster[a] == cid);
    float anyc = bsum2(lbl ? 1.f : 0.f, sm);
    float lsum = bsum2(lbl ? -logf(p) : 0.f, sm);
    if (c == 0) {
        if (anyc == 0.f) lsum += -logf(p0);
        loss_partial[m] = lsum;
    }
}

__global__ void loss_sum(const float* __restrict__ lp, float* __restrict__ out) {
    float v = 0.f;
    for (int i = threadIdx.x; i < 1024; i += 256) v += lp[i];
#pragma unroll
    for (int o = 1; o < 64; o <<= 1) v += __shfl_xor(v, o);
    __shared__ float sm[4];
    if ((threadIdx.x & 63) == 0) sm[threadIdx.x >> 6] = v;
    __syncthreads();
    if (threadIdx.x == 0) out[(size_t)1024 * 129] = sm[0] + sm[1] + sm[2] + sm[3];
}

extern "C" void kernel_launch(void* const* d_in, const int* in_sizes, int n_in,
                              void* d_out, int out_size, void* d_ws, size_t ws_size,
                              hipStream_t stream)
{
    const float* emb   = (const float*)d_in[0];
    const int*   clus  = (const int*)  d_in[1];
    const int*   spk   = (const int*)  d_in[2];
    const float* ms_W0 = (const float*)d_in[3];
    const float* ms_b0 = (const float*)d_in[4];
    const float* ms_W1 = (const float*)d_in[5];
    const float* ms_b1 = (const float*)d_in[6];
    const float* sp_W0 = (const float*)d_in[7];
    const float* sp_b0 = (const float*)d_in[8];
    const float* sp_W1 = (const float*)d_in[9];
    const float* sp_b1 = (const float*)d_in[10];
    const float* spke  = (const float*)d_in[11];
    const float* bkte  = (const float*)d_in[12];

    float* ws = (float*)d_ws;
    float* H        = ws;
    float* slow     = ws + 3145728;
    float* spk_proj = ws + 3276800;
    float* bkt_proj = ws + 3278848;
    float* msc      = ws + 3289088;
    float* lossp    = ws + 3290112;
    ushort* embb    = (ushort*)(ws + 3291136);
    ushort* Wall    = (ushort*)(ws + 3553280);
    ushort* WfragB  = Wall + (size_t)3072 * 512;   // reuse W_prod region, 32x32 frag-major
    float* out = (float*)d_out;

    const int pair_lds = 32 * LDSR * 2 + 8 * 32 * 4 + 3 * 32 * 4;   // 34432 B

    static bool attr_set = false;
    if (!attr_set) {
        hipFuncSetAttribute((const void*)&pair_mfma,
                            hipFuncAttributeMaxDynamicSharedMemorySize,
                            pair_lds);
        attr_set = true;
    }

    hipLaunchKernelGGL(prep_all, dim3(1676), dim3(256), 0, stream,
                       emb, embb, ms_W0, sp_W0, Wall, WfragB,
                       spke, bkte, spk_proj, bkt_proj, msc);
    hipLaunchKernelGGL(gemm_h_ms, dim3(48, 16), dim3(256), 0, stream,
                       embb, Wall, ms_b0, ms_W1, H, msc);
    hipLaunchKernelGGL(pair_mfma, dim3(1024, 4), dim3(512), pair_lds, stream,
                       embb, WfragB, H, spk_proj, bkt_proj, sp_b0, sp_W1, spk, slow);
    hipLaunchKernelGGL(softmax_loss, dim3(1024), dim3(128), 0, stream,
                       slow, msc, ms_b1, sp_b1, clus, out, lossp);
    hipLaunchKernelGGL(loss_sum, dim3(1), dim3(256), 0, stream, lossp, out);
}

// Round 11
// 325.054 us; speedup vs baseline: 1.3343x; 1.3343x over previous
//
#include <hip/hip_runtime.h>
#include <math.h>

// Problem constants (B=1)
#define MM 1024
#define DD 512
#define CC 128
#define LDSR 516   // A row stride in ushorts: 1032 B = 258 dw ≡ 2 (mod 32).
                   // b64 reads/8B stores: uniform 4 accesses/bank/wave = 2/phase -> free.

// ws layout (floats):
//  H[1024][3072]      @ 0        (cols 1024.. src_proj, 2048.. ant_proj; 0..1023 unused)
//  slow[1024][128]    @ 3145728
//  spk_proj[2][1024]  @ 3276800
//  bkt_proj[10][1024] @ 3278848
//  ms[1024]           @ 3289088   (raw dot partials, atomically accumulated; no b1)
//  lossp[1024]        @ 3290112
//  embb bf16[1024][512]  @ 3291136
//  Wall bf16[4096][512]  @ 3553280
//    rows [0,1024)=ms_W0^T, [1024,2048)=W_src^T, [2048,3072)=W_ant^T
//    region [3072,4096) reused as WfragP (pair-contiguous 16x16 fragment-major W_prod):
//      [g2:32][s:16][j:2][lane:64][8] bf16, g2 = wave*4+ft, tile t16 = wave*8+ft*2+j
//      element (f = t16*16 + (lane&15), k = s*32 + ((lane>>4)&3)*8 + e)
//      at byte g2*32768 + s*2048 + j*1024 + lane*16 + e*2

typedef __attribute__((ext_vector_type(8))) short bf16x8;
typedef __attribute__((ext_vector_type(4), aligned(8))) short bf16x4a;
typedef __attribute__((ext_vector_type(4))) float f32x4;

__device__ __forceinline__ ushort bf16_rn(float x) {
    uint u = __float_as_uint(x);
    uint r = u + 0x7fffu + ((u >> 16) & 1u);
    return (ushort)(r >> 16);
}
__device__ __forceinline__ float bf16_to_f(ushort u) {
    return __uint_as_float(((uint)u) << 16);
}
__device__ __forceinline__ bf16x8 ld_lds16(const ushort* p) {   // two ds_read_b64 (8B-aligned)
    bf16x4a lo = *(const bf16x4a*)p;
    bf16x4a hi = *(const bf16x4a*)(p + 4);
    return __builtin_shufflevector(lo, hi, 0, 1, 2, 3, 4, 5, 6, 7);
}

// ---------------- prep_all: emb->bf16 | Wall transpose | WfragP | small projections + ms zero
// grid ranges: [0,1024) emb; [1024,1408) wall; [1408,1664) wfragP; [1664,1676) small_proj
__global__ __launch_bounds__(256) void prep_all(
    const float* __restrict__ emb, ushort* __restrict__ embb,
    const float* __restrict__ ms_W0, const float* __restrict__ sp_W0,
    ushort* __restrict__ Wall, ushort* __restrict__ WfragP,
    const float* __restrict__ speaker_emb, const float* __restrict__ bucket_emb,
    float* __restrict__ spk_proj, float* __restrict__ bkt_proj,
    float* __restrict__ msc)
{
    const int bid = blockIdx.x;
    const int tid = threadIdx.x;

    if (bid < 1024) {                               // ---- prep_emb
        int i = bid * 256 + tid;
        float2 v = ((const float2*)emb)[i];
        ushort2 o;
        o.x = bf16_rn(v.x);
        o.y = bf16_rn(v.y);
        ((ushort2*)embb)[i] = o;
        return;
    }
    if (bid < 1408) {                               // ---- prep_wall
        __shared__ float t[64][65];
        const int r = bid - 1024;                   // 0..383
        const int k0 = (r & 7) * 64;
        const int n0 = (r >> 3) * 64;
        const int g = n0 >> 10;
        const float* src = (g == 0) ? ms_W0 : (sp_W0 + (size_t)(g - 1) * 512 * 1024);
        const int col0 = n0 & 1023;
        const int tr = tid >> 6, tc = tid & 63;
#pragma unroll
        for (int i = 0; i < 16; ++i) {
            int k = tr + i * 4;
            t[k][tc] = src[(size_t)(k0 + k) * 1024 + col0 + tc];
        }
        __syncthreads();
        const int f = tid >> 2;
        const int c4 = tid & 3;
        ushort tmp[16];
#pragma unroll
        for (int j = 0; j < 16; ++j) tmp[j] = bf16_rn(t[c4 * 16 + j][f]);
        uint4* dst = (uint4*)(Wall + (size_t)(n0 + f) * 512 + k0 + c4 * 16);
        dst[0] = *(uint4*)&tmp[0];
        dst[1] = *(uint4*)&tmp[8];
        return;
    }
    if (bid < 1664) {                               // ---- prep_wfragP (4 b4 per block)
        const int b4 = (bid - 1408) * 4 + (tid >> 6);   // 0..1023 = g2*32 + s*2 + j
        const int l = tid & 63;
        const int g2 = b4 >> 5, s = (b4 >> 1) & 15, j = b4 & 1;
        const int wv = g2 >> 2, ft = g2 & 3;
        const int t16 = wv * 8 + ft * 2 + j;
        const int f = t16 * 16 + (l & 15);
        const int kb = s * 32 + ((l >> 4) & 3) * 8;
        const float* W = sp_W0 + (size_t)1024 * 1024;   // W_prod [k=512][f=1024]
        ushort tmp[8];
#pragma unroll
        for (int e = 0; e < 8; ++e) tmp[e] = bf16_rn(W[(size_t)(kb + e) * 1024 + f]);
        uint4* dst = (uint4*)(WfragP + (size_t)b4 * 512 + l * 8);
        *dst = *(uint4*)&tmp[0];
        return;
    }
    {                                               // ---- small_proj (+ msc zero in r==0)
        const int r = bid - 1664;                   // 0..11
        if (r == 0) {
            for (int i = tid; i < 1024; i += 256) msc[i] = 0.f;
        }
        const float* e; const float* W; float* out;
        if (r < 2) { e = speaker_emb + r * 20; W = sp_W0 + (size_t)1536 * 1024; out = spk_proj + r * 1024; }
        else       { e = bucket_emb + (r - 2) * 20; W = sp_W0 + (size_t)1556 * 1024; out = bkt_proj + (r - 2) * 1024; }
        float ek[20];
#pragma unroll
        for (int k = 0; k < 20; ++k) ek[k] = e[k];
        for (int f = tid; f < 1024; f += 256) {
            float s = 0.f;
#pragma unroll
            for (int k = 0; k < 20; ++k) s = fmaf(ek[k], W[(size_t)k * 1024 + f], s);
            out[f] = s;
        }
        return;
    }
}

// ---------------- H = emb @ [ms_W0 | W_src | W_ant] via MFMA, 64x64 tiles (768 blocks
// -> 3 blocks/CU). ms-hidden region (n<1024) consumed in-register -> atomicAdd(ms).
__global__ __launch_bounds__(256) void gemm_h_ms(
    const ushort* __restrict__ embb, const ushort* __restrict__ Wall,
    const float* __restrict__ ms_b0, const float* __restrict__ ms_W1,
    float* __restrict__ H, float* __restrict__ ms)
{
    const int n0 = blockIdx.x * 64;   // 48
    const int m0 = blockIdx.y * 64;   // 16
    const int lane = threadIdx.x & 63, wave = threadIdx.x >> 6;
    const int wx = wave & 1, wy = wave >> 1;
    const int l15 = lane & 15, lq = lane >> 4;

    const ushort* arow[2];
#pragma unroll
    for (int mi = 0; mi < 2; ++mi)
        arow[mi] = embb + (size_t)(m0 + wy * 32 + mi * 16 + l15) * 512;
    const ushort* brow[2];
#pragma unroll
    for (int ni = 0; ni < 2; ++ni)
        brow[ni] = Wall + (size_t)(n0 + wx * 32 + ni * 16 + l15) * 512;

    f32x4 acc[2][2];
#pragma unroll
    for (int i = 0; i < 2; ++i)
#pragma unroll
        for (int j = 0; j < 2; ++j) acc[i][j] = (f32x4)0.f;

    for (int kt = 0; kt < 512; kt += 32) {
        const int ko = kt + lq * 8;
        bf16x8 av[2], bv[2];
#pragma unroll
        for (int mi = 0; mi < 2; ++mi) av[mi] = *(const bf16x8*)(arow[mi] + ko);
#pragma unroll
        for (int ni = 0; ni < 2; ++ni) bv[ni] = *(const bf16x8*)(brow[ni] + ko);
#pragma unroll
        for (int mi = 0; mi < 2; ++mi)
#pragma unroll
            for (int ni = 0; ni < 2; ++ni)
                acc[mi][ni] = __builtin_amdgcn_mfma_f32_16x16x32_bf16(av[mi], bv[ni], acc[mi][ni], 0, 0, 0);
    }

    if (n0 < 1024) {
        float b0v[2], w1v[2];
#pragma unroll
        for (int ni = 0; ni < 2; ++ni) {
            const int col = n0 + wx * 32 + ni * 16 + l15;
            b0v[ni] = ms_b0[col];
            w1v[ni] = ms_W1[col];
        }
#pragma unroll
        for (int mi = 0; mi < 2; ++mi)
#pragma unroll
            for (int r = 0; r < 4; ++r) {
                float s = 0.f;
#pragma unroll
                for (int ni = 0; ni < 2; ++ni)
                    s += fmaxf(acc[mi][ni][r] + b0v[ni], 0.f) * w1v[ni];
                s += __shfl_xor(s, 1); s += __shfl_xor(s, 2);
                s += __shfl_xor(s, 4); s += __shfl_xor(s, 8);
                if (l15 == 0) {
                    const int mrow = m0 + wy * 32 + mi * 16 + lq * 4 + r;
                    atomicAdd(&ms[mrow], s);
                }
            }
    } else {
#pragma unroll
        for (int mi = 0; mi < 2; ++mi)
#pragma unroll
            for (int r = 0; r < 4; ++r) {
                int mrow = m0 + wy * 32 + mi * 16 + lq * 4 + r;
#pragma unroll
                for (int ni = 0; ni < 2; ++ni)
                    H[(size_t)mrow * 3072 + n0 + wx * 32 + ni * 16 + l15] = acc[mi][ni][r];
            }
    }
}

// ---------------- pair scorer v11: REVERT to r8/r9-proven 16x16 k-loop (4 independent
// MFMAs/step -> ILP hides L2 B-latency; r10's single 32x32 dep-chain was latency-bound,
// VGPR 28 = no pipelining). Kept from r10's attempt: LDS meta precompute (a*3072,
// bk<<10) + srcb folded into speaker-select constants (kills per-reg VALU addr chains).
// Grid (1024 m, 4 cq); 512 thr / 8 waves; A-tile 32c x 512k -> 4 blocks/CU @ 8 w/SIMD.
__global__ __launch_bounds__(512, 8) void pair_mfma(
    const ushort* __restrict__ embb, const ushort* __restrict__ WfragP,
    const float* __restrict__ H, const float* __restrict__ spk_proj,
    const float* __restrict__ bkt_proj, const float* __restrict__ sp_b0,
    const float* __restrict__ sp_W1, const int* __restrict__ speaker,
    float* __restrict__ slow)
{
    extern __shared__ ushort Alds[];                  // 32*LDSR ushorts
    float* red = (float*)(Alds + 32 * LDSR);          // 8*32 floats
    int* meta_ai = (int*)(red + 8 * 32);              // 32 ints: a*3072
    int* meta_sb = meta_ai + 32;                      // 32 ints: same-speaker flag
    int* meta_bi = meta_sb + 32;                      // 32 ints: bucket<<10
    const int m = blockIdx.x;
    const int cq = blockIdx.y;                        // c-quarter
    const int cbase = cq * 32;
    const int tid = threadIdx.x;
    const int spk_m = speaker[m];

    // ---- build A[c][k] = bf16(em[k]*ea[k]) in LDS + per-c metadata (32 rows)
    {
        const int c = tid & 31;
        const int kh = (tid >> 5) * 32;               // 16 chunks of 32 ushorts
        int a = m - 1 - (cbase + c); if (a < 0) a = 0;
        const ushort* ea = embb + (size_t)a * 512 + kh;
        const ushort* em = embb + (size_t)m * 512 + kh;
        ushort* dst = Alds + c * LDSR + kh;
#pragma unroll
        for (int j = 0; j < 32; j += 8) {
            bf16x8 va = *(const bf16x8*)(ea + j);
            bf16x8 vm = *(const bf16x8*)(em + j);
            uint pr[4];
#pragma unroll
            for (int p = 0; p < 4; ++p) {
                float q0 = bf16_to_f((ushort)va[2 * p])     * bf16_to_f((ushort)vm[2 * p]);
                float q1 = bf16_to_f((ushort)va[2 * p + 1]) * bf16_to_f((ushort)vm[2 * p + 1]);
                pr[p] = __builtin_amdgcn_perm(__float_as_uint(q1), __float_as_uint(q0), 0x07060302u);
            }
            *(uint2*)(dst + j)     = *(uint2*)&pr[0];   // 8B stores (rows are 8B-aligned)
            *(uint2*)(dst + j + 4) = *(uint2*)&pr[2];
        }
        if (tid < 32) {                               // c == tid, a as computed above
            meta_sb[c] = (speaker[a] == spk_m) ? 1 : 0;
            meta_ai[c] = a * 3072;
            int off = cbase + c + 1;                  // 1..128
            int bk;
            if (off <= 4) bk = off;
            else { bk = 31 - __clz(off) + 3; if (bk > 9) bk = 9; }
            meta_bi[c] = bk << 10;
        }
    }
    __syncthreads();

    const int lane = tid & 63;
    const int wave = __builtin_amdgcn_readfirstlane(tid >> 6);   // 0..7, wave-uniform
    const int l15 = lane & 15, lq = lane >> 4;
    const ushort* ab0 = Alds + l15 * LDSR + lq * 8;   // ct=0; ct=1 at +16*LDSR

    const float* Hsrc = H + m * 3072 + 1024;          // block-uniform
    const float* Hant = H + 2048;

    float sacc[2][4];
#pragma unroll
    for (int ct = 0; ct < 2; ++ct)
#pragma unroll
        for (int r = 0; r < 4; ++r) sacc[ct][r] = 0.f;

#pragma unroll 1
    for (int ft = 0; ft < 4; ++ft) {
        const int f0a = wave * 128 + ft * 32;
        // B: pair-contiguous; b0/b1 at +0/+1024B, s-stride 2048B (imm-foldable)
        const ushort* bb = WfragP + (size_t)(wave * 4 + ft) * 16384 + (size_t)lane * 8;
        f32x4 acc[2][2];
#pragma unroll
        for (int i = 0; i < 2; ++i)
#pragma unroll
            for (int j = 0; j < 2; ++j) acc[i][j] = (f32x4)0.f;

#pragma unroll 4
        for (int s = 0; s < 16; ++s) {
            bf16x8 b0 = *(const bf16x8*)(bb + s * 1024);
            bf16x8 b1 = *(const bf16x8*)(bb + s * 1024 + 512);
            bf16x8 a0 = ld_lds16(ab0 + s * 32);
            bf16x8 a1 = ld_lds16(ab0 + 16 * LDSR + s * 32);
            __builtin_amdgcn_s_setprio(1);
            acc[0][0] = __builtin_amdgcn_mfma_f32_16x16x32_bf16(a0, b0, acc[0][0], 0, 0, 0);
            acc[0][1] = __builtin_amdgcn_mfma_f32_16x16x32_bf16(a0, b1, acc[0][1], 0, 0, 0);
            acc[1][0] = __builtin_amdgcn_mfma_f32_16x16x32_bf16(a1, b0, acc[1][0], 0, 0, 0);
            acc[1][1] = __builtin_amdgcn_mfma_f32_16x16x32_bf16(a1, b1, acc[1][1], 0, 0, 0);
            __builtin_amdgcn_s_setprio(0);
        }

        // ---- per-ft epilogue: fold into sacc (reduce deferred past the ft loop)
        float w1v[2], sp0v[2], sp1v[2];
#pragma unroll
        for (int fi = 0; fi < 2; ++fi) {
            const int fcol = f0a + fi * 16 + l15;
            const float srcb = Hsrc[fcol] + sp_b0[fcol];
            w1v[fi]  = sp_W1[fcol];
            sp0v[fi] = spk_proj[fcol] + srcb;
            sp1v[fi] = spk_proj[1024 + fcol] + srcb;
        }
        // C/D 16x16 layout: col(f) = lane&15, row(c) = lq*4 + reg
#pragma unroll
        for (int ct = 0; ct < 2; ++ct) {
#pragma unroll
            for (int reg = 0; reg < 4; ++reg) {
                const int cl = ct * 16 + lq * 4 + reg;        // 0..31 local
                const int ss = meta_sb[cl];
                const int aidx = meta_ai[cl];
                const int bidx = meta_bi[cl];
                float s = sacc[ct][reg];
#pragma unroll
                for (int fi = 0; fi < 2; ++fi) {
                    const int fcol = f0a + fi * 16 + l15;
                    float pre = acc[ct][fi][reg] + (ss ? sp1v[fi] : sp0v[fi])
                              + Hant[aidx + fcol] + bkt_proj[bidx + fcol];
                    s += fmaxf(pre, 0.f) * w1v[fi];
                }
                sacc[ct][reg] = s;
            }
        }
    }

    // ---- single deferred reduce per (ct,reg): 8 chains/wave
#pragma unroll
    for (int ct = 0; ct < 2; ++ct) {
#pragma unroll
        for (int reg = 0; reg < 4; ++reg) {
            float s = sacc[ct][reg];
            s += __shfl_xor(s, 1); s += __shfl_xor(s, 2);
            s += __shfl_xor(s, 4); s += __shfl_xor(s, 8);
            if (l15 == 0) red[wave * 32 + ct * 16 + lq * 4 + reg] = s;
        }
    }
    __syncthreads();
    if (tid < 32) {
        float s = 0.f;
#pragma unroll
        for (int i = 0; i < 8; ++i) s += red[i * 32 + tid];
        slow[m * 128 + cbase + tid] = s;
    }
}

// ---------------- softmax + per-mention loss (ms = raw dots; b1 added here, 2x)
__device__ __forceinline__ float bsum2(float v, float* sm) {
#pragma unroll
    for (int o = 1; o < 64; o <<= 1) v += __shfl_xor(v, o);
    __syncthreads();
    if ((threadIdx.x & 63) == 0) sm[threadIdx.x >> 6] = v;
    __syncthreads();
    return sm[0] + sm[1];
}
__device__ __forceinline__ float bmax2(float v, float* sm) {
#pragma unroll
    for (int o = 1; o < 64; o <<= 1) v = fmaxf(v, __shfl_xor(v, o));
    __syncthreads();
    if ((threadIdx.x & 63) == 0) sm[threadIdx.x >> 6] = v;
    __syncthreads();
    return fmaxf(sm[0], sm[1]);
}

__global__ __launch_bounds__(128) void softmax_loss(
    const float* __restrict__ slow, const float* __restrict__ ms,
    const float* __restrict__ ms_b1,
    const float* __restrict__ sp_b1, const int* __restrict__ cluster,
    float* __restrict__ out, float* __restrict__ loss_partial)
{
    const int m = blockIdx.x, c = threadIdx.x;
    __shared__ float sm[2];
    const int raw = m - 1 - c;
    const bool maskv = raw >= 0;
    const int a = maskv ? raw : 0;
    float score = slow[(size_t)m * 128 + c] + sp_b1[0]
                + ms[m] + ms[a] + 2.f * ms_b1[0];
    if (!maskv) score = -INFINITY;

    float mx = fmaxf(bmax2(score, sm), 0.f);
    float e = expf(score - mx);
    float e0 = expf(0.f - mx);
    float sum = bsum2(e, sm) + e0;
    float p = e / sum, p0 = e0 / sum;
    const float eps = 1e-6f;
    p  = fminf(fmaxf(p,  eps), 1.f - eps);
    p0 = fminf(fmaxf(p0, eps), 1.f - eps);
    float sum2 = bsum2(p, sm) + p0;
    p /= sum2; p0 /= sum2;
    out[(size_t)m * 129 + 1 + c] = p;
    if (c == 0) out[(size_t)m * 129] = p0;

    const int cid = cluster[m];
    const bool lbl = maskv && (cid > 0) && (cluster[a] == cid);
    float anyc = bsum2(lbl ? 1.f : 0.f, sm);
    float lsum = bsum2(lbl ? -logf(p) : 0.f, sm);
    if (c == 0) {
        if (anyc == 0.f) lsum += -logf(p0);
        loss_partial[m] = lsum;
    }
}

__global__ void loss_sum(const float* __restrict__ lp, float* __restrict__ out) {
    float v = 0.f;
    for (int i = threadIdx.x; i < 1024; i += 256) v += lp[i];
#pragma unroll
    for (int o = 1; o < 64; o <<= 1) v += __shfl_xor(v, o);
    __shared__ float sm[4];
    if ((threadIdx.x & 63) == 0) sm[threadIdx.x >> 6] = v;
    __syncthreads();
    if (threadIdx.x == 0) out[(size_t)1024 * 129] = sm[0] + sm[1] + sm[2] + sm[3];
}

extern "C" void kernel_launch(void* const* d_in, const int* in_sizes, int n_in,
                              void* d_out, int out_size, void* d_ws, size_t ws_size,
                              hipStream_t stream)
{
    const float* emb   = (const float*)d_in[0];
    const int*   clus  = (const int*)  d_in[1];
    const int*   spk   = (const int*)  d_in[2];
    const float* ms_W0 = (const float*)d_in[3];
    const float* ms_b0 = (const float*)d_in[4];
    const float* ms_W1 = (const float*)d_in[5];
    const float* ms_b1 = (const float*)d_in[6];
    const float* sp_W0 = (const float*)d_in[7];
    const float* sp_b0 = (const float*)d_in[8];
    const float* sp_W1 = (const float*)d_in[9];
    const float* sp_b1 = (const float*)d_in[10];
    const float* spke  = (const float*)d_in[11];
    const float* bkte  = (const float*)d_in[12];

    float* ws = (float*)d_ws;
    float* H        = ws;
    float* slow     = ws + 3145728;
    float* spk_proj = ws + 3276800;
    float* bkt_proj = ws + 3278848;
    float* msc      = ws + 3289088;
    float* lossp    = ws + 3290112;
    ushort* embb    = (ushort*)(ws + 3291136);
    ushort* Wall    = (ushort*)(ws + 3553280);
    ushort* WfragP  = Wall + (size_t)3072 * 512;   // reuse W_prod region, pair-frag-major
    float* out = (float*)d_out;

    const int pair_lds = 32 * LDSR * 2 + 8 * 32 * 4 + 3 * 32 * 4;   // 34432 B

    static bool attr_set = false;
    if (!attr_set) {
        hipFuncSetAttribute((const void*)&pair_mfma,
                            hipFuncAttributeMaxDynamicSharedMemorySize,
                            pair_lds);
        attr_set = true;
    }

    hipLaunchKernelGGL(prep_all, dim3(1676), dim3(256), 0, stream,
                       emb, embb, ms_W0, sp_W0, Wall, WfragP,
                       spke, bkte, spk_proj, bkt_proj, msc);
    hipLaunchKernelGGL(gemm_h_ms, dim3(48, 16), dim3(256), 0, stream,
                       embb, Wall, ms_b0, ms_W1, H, msc);
    hipLaunchKernelGGL(pair_mfma, dim3(1024, 4), dim3(512), pair_lds, stream,
                       embb, WfragP, H, spk_proj, bkt_proj, sp_b0, sp_W1, spk, slow);
    hipLaunchKernelGGL(softmax_loss, dim3(1024), dim3(128), 0, stream,
                       slow, msc, ms_b1, sp_b1, clus, out, lossp);
    hipLaunchKernelGGL(loss_sum, dim3(1), dim3(256), 0, stream, lossp, out);
}